// Round 11
// baseline (112.018 us; speedup 1.0000x reference)
//
#include <hip/hip_runtime.h>
#include <hip/hip_bf16.h>

#define B_    8
#define N_    9225
#define M_    4096
#define K_    32
#define HID_  64
#define DOUT_ 16

typedef __attribute__((ext_vector_type(8))) short short8;
typedef __attribute__((ext_vector_type(4))) float floatx4;
typedef __attribute__((ext_vector_type(2))) float f32x2;

static __device__ __forceinline__ short f2bf(float f) {
    __hip_bfloat16 h = __float2bfloat16(f);
    return __builtin_bit_cast(short, h);
}
static __device__ __forceinline__ f32x2 splat2(float v) { return (f32x2){v, v}; }
static __device__ __forceinline__ int bpermi(int src_bytes, int v) {
    return __builtin_amdgcn_ds_bpermute(src_bytes, v);
}
static __device__ __forceinline__ float bpermf(int src_bytes, float v) {
    return __builtin_bit_cast(float,
        __builtin_amdgcn_ds_bpermute(src_bytes, __builtin_bit_cast(int, v)));
}

// Sum over each 16-lane DPP row via row_shr tree; lane (row*16+15) holds the sum.
static __device__ __forceinline__ float row16_sum(float v) {
    int t;
    t = __builtin_amdgcn_update_dpp(0, __builtin_bit_cast(int, v), 0x111, 0xF, 0xF, true);
    v += __builtin_bit_cast(float, t);
    t = __builtin_amdgcn_update_dpp(0, __builtin_bit_cast(int, v), 0x112, 0xF, 0xF, true);
    v += __builtin_bit_cast(float, t);
    t = __builtin_amdgcn_update_dpp(0, __builtin_bit_cast(int, v), 0x114, 0xF, 0xF, true);
    v += __builtin_bit_cast(float, t);
    t = __builtin_amdgcn_update_dpp(0, __builtin_bit_cast(int, v), 0x118, 0xF, 0xF, true);
    v += __builtin_bit_cast(float, t);
    return v;
}

// gelu(x) ~ 0.5*x*(1 + tanh(z)), z = x*(0.79788456 + 0.035677408*x^2),
// tanh via Pade(5,4), clamped to [-1,1]. No v_exp. (Validated R4/R5/R8.)
static __device__ __forceinline__ f32x2 gelu2(f32x2 x) {
    const f32x2 xsq = x * x;
    const f32x2 t   = __builtin_elementwise_fma(xsq, splat2(0.035677408f), splat2(0.79788456f));
    const f32x2 z   = x * t;
    const f32x2 u   = z * z;
    const f32x2 a   = u + splat2(105.0f);
    const f32x2 nin = __builtin_elementwise_fma(u, a, splat2(945.0f));
    const f32x2 num = z * nin;
    const f32x2 bq  = __builtin_elementwise_fma(u, splat2(15.0f), splat2(420.0f));
    const f32x2 den = __builtin_elementwise_fma(u, bq, splat2(945.0f));
    const f32x2 r   = { __builtin_amdgcn_rcpf(den[0]), __builtin_amdgcn_rcpf(den[1]) };
    f32x2 th = num * r;
    th = __builtin_elementwise_min(__builtin_elementwise_max(th, splat2(-1.0f)), splat2(1.0f));
    const f32x2 hx = x * splat2(0.5f);
    return __builtin_elementwise_fma(hx, th, hx);
}

// ILP-DOUBLED R8: each wave owns 4 rows = two independent pairs A (rows 0-1)
// and B (rows 2-3), marched through the phase loop together with A/B
// instructions interleaved. Rationale: R2-R10 pinned at ~41us with VALUBusy
// ~52% across VALU-heavy, DS-heavy, prefetched, and persistent variants --
// the stall is intra-wave dependency bubbles in each phase's single long
// chain (bperm->lgkm->h->gelu->f2bf->MFMA->epilogue). Two chains per wave
// let the scheduler fill one chain's bubbles with the other's instructions.
// W1/b1 LDS reads are shared between chains (same j) -> DS per unit work
// halves. Compute per chain is byte-identical to validated R8.
__global__ __launch_bounds__(256) void it_kernel(
    const float* __restrict__ y,
    const float* __restrict__ x,
    const float* __restrict__ f_y,
    const float* __restrict__ weights,
    const float* __restrict__ W1,   // [4][64] row-major
    const float* __restrict__ b1,   // [64]
    const float* __restrict__ W2,   // [64][16] row-major
    const float* __restrict__ b2,   // [16]
    const int*   __restrict__ nbr,  // [B][M][K] int32
    float*       __restrict__ out)  // [B][M][16]
{
    __shared__ float W1L[4][64];
    __shared__ float b1L[64];
    __shared__ float b2L[16];

    const int tid  = threadIdx.x;
    W1L[tid >> 6][tid & 63] = W1[tid];
    if (tid < 64) b1L[tid] = b1[tid];
    if (tid < 16) b2L[tid] = b2[tid];

    const int lane = tid & 63;
    const int q    = lane >> 4;    // quad 0..3
    const int nlo  = lane & 15;    // neighbor-within-half; also c for W2 A-frag
    const int row0 = __builtin_amdgcn_readfirstlane((blockIdx.x * 4 + (tid >> 6)) * 4);
    const int bbase = (row0 >> 12) * N_;   // M=4096; rows 0..3 same batch

    // ---- dedup gathers for BOTH pairs: lane g = (row g>>5, nbr g&31) ----
    const int r_g = lane >> 5, kk = lane & 31;
    const int rawA = nbr[(size_t)(row0 + r_g) * K_ + kk];
    const int rawB = nbr[(size_t)(row0 + 2 + r_g) * K_ + kk];
    const int vldA = rawA >= 0,            vldB = rawB >= 0;
    const int bn_gA = bbase + (vldA ? rawA : 0);
    const int bn_gB = bbase + (vldB ? rawB : 0);
    const float2 yvgA = *(const float2*)(y + (size_t)bn_gA * 2);
    const float2 yvgB = *(const float2*)(y + (size_t)bn_gB * 2);
    const float  wgA  = vldA ? weights[bn_gA] : 0.0f;
    const float  wgB  = vldB ? weights[bn_gB] : 0.0f;

    float2 xvr[4];
    #pragma unroll
    for (int i = 0; i < 4; ++i)
        xvr[i] = *(const float2*)(x + (size_t)(row0 + i) * 2);

    // ---- W2 A-fragment: lane holds A[m=c=nlo][k=q*8+jj] = W2[j][nlo], bf16 ----
    short8 w2f[2];
    #pragma unroll
    for (int ch = 0; ch < 2; ++ch)
        #pragma unroll
        for (int jj = 0; jj < 8; ++jj)
            w2f[ch][jj] = f2bf(W2[(ch*32 + q*8 + jj) * DOUT_ + nlo]);

    __syncthreads();   // W1L/b1L/b2L visible to all 4 waves

    float pA[4] = {0.f, 0.f, 0.f, 0.f};
    float pB[4] = {0.f, 0.f, 0.f, 0.f};
    #pragma unroll
    for (int ph = 0; ph < 4; ++ph) {
        const int it = ph >> 1, h = ph & 1;
        const int src = ((it << 5) + (h << 4) + nlo) << 2;

        // both chains' f_y gathers issued first; h-stage covers them
        const int bnA = bpermi(src, bn_gA);
        const int bnB = bpermi(src, bn_gB);
        const floatx4 fvA = *(const floatx4*)(f_y + (size_t)bnA * 16 + q * 4);
        const floatx4 fvB = *(const floatx4*)(f_y + (size_t)bnB * 16 + q * 4);

        // redistribute both chains' y / weight to (q,nlo) layout
        f32x2 yvA, yvB;
        yvA[0] = bpermf(src, yvgA.x);  yvB[0] = bpermf(src, yvgB.x);
        yvA[1] = bpermf(src, yvgA.y);  yvB[1] = bpermf(src, yvgB.y);
        const float sA = bpermf(src, wgA);
        const float sB = bpermf(src, wgB);
        const float2 xvA = xvr[it];
        const float2 xvB = xvr[2 + it];

        short8 hfA[2], hfB[2];
        #pragma unroll
        for (int ch = 0; ch < 2; ++ch) {
            #pragma unroll
            for (int p = 0; p < 4; ++p) {
                const int j = ch*32 + q*8 + 2*p;
                const f32x2 b1v  = *(const f32x2*)&b1L[j];       // shared loads
                const f32x2 w1a  = *(const f32x2*)&W1L[0][j];
                const f32x2 w1b  = *(const f32x2*)&W1L[1][j];
                const f32x2 w1c  = *(const f32x2*)&W1L[2][j];
                const f32x2 w1d  = *(const f32x2*)&W1L[3][j];
                f32x2 hA = b1v, hB = b1v;
                hA = __builtin_elementwise_fma(splat2(yvA[0]), w1a, hA);
                hB = __builtin_elementwise_fma(splat2(yvB[0]), w1a, hB);
                hA = __builtin_elementwise_fma(splat2(yvA[1]), w1b, hA);
                hB = __builtin_elementwise_fma(splat2(yvB[1]), w1b, hB);
                hA = __builtin_elementwise_fma(splat2(xvA.x),  w1c, hA);
                hB = __builtin_elementwise_fma(splat2(xvB.x),  w1c, hB);
                hA = __builtin_elementwise_fma(splat2(xvA.y),  w1d, hA);
                hB = __builtin_elementwise_fma(splat2(xvB.y),  w1d, hB);
                const f32x2 gA = gelu2(hA);
                const f32x2 gB = gelu2(hB);
                hfA[ch][2*p]     = f2bf(gA[0]);
                hfB[ch][2*p]     = f2bf(gB[0]);
                hfA[ch][2*p + 1] = f2bf(gA[1]);
                hfB[ch][2*p + 1] = f2bf(gB[1]);
            }
        }
        floatx4 accA = *(const floatx4*)&b2L[q*4];
        floatx4 accB = accA;
        accA = __builtin_amdgcn_mfma_f32_16x16x32_bf16(w2f[0], hfA[0], accA, 0, 0, 0);
        accB = __builtin_amdgcn_mfma_f32_16x16x32_bf16(w2f[0], hfB[0], accB, 0, 0, 0);
        accA = __builtin_amdgcn_mfma_f32_16x16x32_bf16(w2f[1], hfA[1], accA, 0, 0, 0);
        accB = __builtin_amdgcn_mfma_f32_16x16x32_bf16(w2f[1], hfB[1], accB, 0, 0, 0);
        #pragma unroll
        for (int r4 = 0; r4 < 4; ++r4) {
            pA[r4] = fmaf(accA[r4], fvA[r4] * sA, pA[r4]);
            pB[r4] = fmaf(accB[r4], fvB[r4] * sB, pB[r4]);
        }

        if (h == 1) {   // finished a row in each chain: reduce + store both
            #pragma unroll
            for (int r4 = 0; r4 < 4; ++r4) {
                pA[r4] = row16_sum(pA[r4]);
                pB[r4] = row16_sum(pB[r4]);
            }
            if (nlo == 15) {
                floatx4 oA = {pA[0], pA[1], pA[2], pA[3]};
                floatx4 oB = {pB[0], pB[1], pB[2], pB[3]};
                *(floatx4*)(out + (size_t)(row0 + it) * DOUT_ + q*4) = oA;
                *(floatx4*)(out + (size_t)(row0 + 2 + it) * DOUT_ + q*4) = oB;
            }
            #pragma unroll
            for (int r4 = 0; r4 < 4; ++r4) { pA[r4] = 0.f; pB[r4] = 0.f; }
        }
    }
}

extern "C" void kernel_launch(void* const* d_in, const int* in_sizes, int n_in,
                              void* d_out, int out_size, void* d_ws, size_t ws_size,
                              hipStream_t stream) {
    const float* y   = (const float*)d_in[0];
    const float* x   = (const float*)d_in[1];
    const float* f_y = (const float*)d_in[2];
    const float* w   = (const float*)d_in[3];
    const float* W1  = (const float*)d_in[4];
    const float* b1  = (const float*)d_in[5];
    const float* W2  = (const float*)d_in[6];
    const float* b2  = (const float*)d_in[7];
    const int*   nbr = (const int*)d_in[8];
    float* out = (float*)d_out;

    // 32768 rows / (4 waves * 4 rows) = 2048 blocks
    dim3 grid(B_ * M_ / 16), block(256);
    hipLaunchKernelGGL(it_kernel, grid, block, 0, stream,
                       y, x, f_y, w, W1, b1, W2, b2, nbr, out);
}

// Round 12
// 106.080 us; speedup vs baseline: 1.0560x; 1.0560x over previous
//
#include <hip/hip_runtime.h>
#include <hip/hip_bf16.h>

#define B_    8
#define N_    9225
#define M_    4096
#define K_    32
#define HID_  64
#define DOUT_ 16

typedef __attribute__((ext_vector_type(8))) short short8;
typedef __attribute__((ext_vector_type(4))) float floatx4;
typedef __attribute__((ext_vector_type(2))) float f32x2;

static __device__ __forceinline__ short f2bf(float f) {
    __hip_bfloat16 h = __float2bfloat16(f);
    return __builtin_bit_cast(short, h);
}
static __device__ __forceinline__ f32x2 splat2(float v) { return (f32x2){v, v}; }
static __device__ __forceinline__ int bpermi(int src_bytes, int v) {
    return __builtin_amdgcn_ds_bpermute(src_bytes, v);
}
static __device__ __forceinline__ float bpermf(int src_bytes, float v) {
    return __builtin_bit_cast(float,
        __builtin_amdgcn_ds_bpermute(src_bytes, __builtin_bit_cast(int, v)));
}

// Sum over each 16-lane DPP row via row_shr tree; lane (row*16+15) holds the sum.
static __device__ __forceinline__ float row16_sum(float v) {
    int t;
    t = __builtin_amdgcn_update_dpp(0, __builtin_bit_cast(int, v), 0x111, 0xF, 0xF, true);
    v += __builtin_bit_cast(float, t);
    t = __builtin_amdgcn_update_dpp(0, __builtin_bit_cast(int, v), 0x112, 0xF, 0xF, true);
    v += __builtin_bit_cast(float, t);
    t = __builtin_amdgcn_update_dpp(0, __builtin_bit_cast(int, v), 0x114, 0xF, 0xF, true);
    v += __builtin_bit_cast(float, t);
    t = __builtin_amdgcn_update_dpp(0, __builtin_bit_cast(int, v), 0x118, 0xF, 0xF, true);
    v += __builtin_bit_cast(float, t);
    return v;
}

// gelu(x) ~ 0.5*x*(1 + tanh(z)), z = x*(0.79788456 + 0.035677408*x^2),
// tanh via Pade(5,4), clamped to [-1,1]. No v_exp. (Validated R4-R11.)
static __device__ __forceinline__ f32x2 gelu2(f32x2 x) {
    const f32x2 xsq = x * x;
    const f32x2 t   = __builtin_elementwise_fma(xsq, splat2(0.035677408f), splat2(0.79788456f));
    const f32x2 z   = x * t;
    const f32x2 u   = z * z;
    const f32x2 a   = u + splat2(105.0f);
    const f32x2 nin = __builtin_elementwise_fma(u, a, splat2(945.0f));
    const f32x2 num = z * nin;
    const f32x2 bq  = __builtin_elementwise_fma(u, splat2(15.0f), splat2(420.0f));
    const f32x2 den = __builtin_elementwise_fma(u, bq, splat2(945.0f));
    const f32x2 r   = { __builtin_amdgcn_rcpf(den[0]), __builtin_amdgcn_rcpf(den[1]) };
    f32x2 th = num * r;
    th = __builtin_elementwise_min(__builtin_elementwise_max(th, splat2(-1.0f)), splat2(1.0f));
    const f32x2 hx = x * splat2(0.5f);
    return __builtin_elementwise_fma(hx, th, hx);
}

// XCD-PINNED R9: batch = blockIdx & 7 so (with the %8 round-robin block->XCD
// heuristic) XCD b only ever gathers batch b's tables (f_y 590KB + y 74KB +
// w 37KB ~ 0.7MB, fits the 4MB per-XCD L2). R2-R11 evidence: time pinned at
// ~41-44us across compute/ILP/occupancy/prefetch variants; warm replays with
// FETCH~0 ran identically -> gathers stall at L3/cross-XCD distance, not HBM.
// This mapping converts every y/w/f_y gather from ~600+cyc L3 to ~200cyc
// local-L2 after first touch, and removes ~8x cross-XCD duplication
// (FETCH 23.5MB -> ~ideal 11MB). Compute identical to validated R9.
__global__ __launch_bounds__(256) void it_kernel(
    const float* __restrict__ y,
    const float* __restrict__ x,
    const float* __restrict__ f_y,
    const float* __restrict__ weights,
    const float* __restrict__ W1,   // [4][64] row-major
    const float* __restrict__ b1,   // [64]
    const float* __restrict__ W2,   // [64][16] row-major
    const float* __restrict__ b2,   // [16]
    const int*   __restrict__ nbr,  // [B][M][K] int32
    float*       __restrict__ out)  // [B][M][16]
{
    __shared__ float W1L[4][64];
    __shared__ float b1L[64];
    __shared__ float b2L[16];

    const int tid  = threadIdx.x;
    W1L[tid >> 6][tid & 63] = W1[tid];
    if (tid < 64) b1L[tid] = b1[tid];
    if (tid < 16) b2L[tid] = b2[tid];

    const int lane = tid & 63;
    const int q    = lane >> 4;    // quad 0..3
    const int nlo  = lane & 15;    // neighbor-within-half; also c for W2 A-frag
    // ---- XCD-pinned mapping: batch = blk & 7 (round-robin XCD heuristic) ----
    const int blk   = blockIdx.x;
    const int batch = blk & 7;
    const int pidx  = (blk >> 3) * 4 + (tid >> 6);   // pair index within batch
    const int row0  = __builtin_amdgcn_readfirstlane(batch * M_ + pidx * 2);
    const int bbase = batch * N_;

    // ---- dedup gather: lane g covers (row g>>5, neighbor g&31) ----
    const int r_g = lane >> 5, kk = lane & 31;
    const int raw = nbr[(size_t)(row0 + r_g) * K_ + kk];
    const int vld = raw >= 0;
    const int bn_g = bbase + (vld ? raw : 0);
    const float2 yvg = *(const float2*)(y + (size_t)bn_g * 2);
    const float  wg  = vld ? weights[bn_g] : 0.0f;

    // ---- W2 A-fragment: lane holds A[m=c=nlo][k=q*8+jj] = W2[j][nlo], bf16 ----
    short8 w2f[2];
    #pragma unroll
    for (int ch = 0; ch < 2; ++ch)
        #pragma unroll
        for (int jj = 0; jj < 8; ++jj)
            w2f[ch][jj] = f2bf(W2[(ch*32 + q*8 + jj) * DOUT_ + nlo]);

    __syncthreads();   // W1L/b1L/b2L visible to all 4 waves

    float partial[4] = {0.f, 0.f, 0.f, 0.f};
    #pragma unroll
    for (int ph = 0; ph < 4; ++ph) {
        const int it = ph >> 1, h = ph & 1;
        const int src = ((it << 5) + (h << 4) + nlo) << 2;

        // this phase's f_y gather issued first; h-stage covers it
        const int bn = bpermi(src, bn_g);
        const floatx4 fv = *(const floatx4*)(f_y + (size_t)bn * 16 + q * 4);

        // redistribute this phase's y / weight to (q,nlo) layout
        f32x2 yv;
        yv[0] = bpermf(src, yvg.x);
        yv[1] = bpermf(src, yvg.y);
        const float s = bpermf(src, wg);
        const float2 xv = *(const float2*)(x + (size_t)(row0 + it) * 2);  // L1-hot

        short8 hf[2];
        #pragma unroll
        for (int ch = 0; ch < 2; ++ch) {
            #pragma unroll
            for (int p = 0; p < 4; ++p) {
                const int j = ch*32 + q*8 + 2*p;
                f32x2 hin = *(const f32x2*)&b1L[j];
                hin = __builtin_elementwise_fma(splat2(yv[0]), *(const f32x2*)&W1L[0][j], hin);
                hin = __builtin_elementwise_fma(splat2(yv[1]), *(const f32x2*)&W1L[1][j], hin);
                hin = __builtin_elementwise_fma(splat2(xv.x),  *(const f32x2*)&W1L[2][j], hin);
                hin = __builtin_elementwise_fma(splat2(xv.y),  *(const f32x2*)&W1L[3][j], hin);
                const f32x2 g = gelu2(hin);
                hf[ch][2*p]     = f2bf(g[0]);
                hf[ch][2*p + 1] = f2bf(g[1]);
            }
        }
        floatx4 acc = *(const floatx4*)&b2L[q*4];   // broadcast LDS read
        acc = __builtin_amdgcn_mfma_f32_16x16x32_bf16(w2f[0], hf[0], acc, 0, 0, 0);
        acc = __builtin_amdgcn_mfma_f32_16x16x32_bf16(w2f[1], hf[1], acc, 0, 0, 0);
        #pragma unroll
        for (int r4 = 0; r4 < 4; ++r4)
            partial[r4] = fmaf(acc[r4], fv[r4] * s, partial[r4]);

        if (h == 1) {   // finished a row: reduce over 16 neighbors, store
            #pragma unroll
            for (int r4 = 0; r4 < 4; ++r4)
                partial[r4] = row16_sum(partial[r4]);
            if (nlo == 15) {
                floatx4 o = {partial[0], partial[1], partial[2], partial[3]};
                *(floatx4*)(out + (size_t)(row0 + it) * DOUT_ + q*4) = o;
            }
            #pragma unroll
            for (int r4 = 0; r4 < 4; ++r4) partial[r4] = 0.f;
        }
    }
}

extern "C" void kernel_launch(void* const* d_in, const int* in_sizes, int n_in,
                              void* d_out, int out_size, void* d_ws, size_t ws_size,
                              hipStream_t stream) {
    const float* y   = (const float*)d_in[0];
    const float* x   = (const float*)d_in[1];
    const float* f_y = (const float*)d_in[2];
    const float* w   = (const float*)d_in[3];
    const float* W1  = (const float*)d_in[4];
    const float* b1  = (const float*)d_in[5];
    const float* W2  = (const float*)d_in[6];
    const float* b2  = (const float*)d_in[7];
    const int*   nbr = (const int*)d_in[8];
    float* out = (float*)d_out;

    // 4096 blocks: 512 per batch, interleaved so batch = blockIdx % 8 -> XCD
    dim3 grid(B_ * M_ / 8), block(256);
    hipLaunchKernelGGL(it_kernel, grid, block, 0, stream,
                       y, x, f_y, w, W1, b1, W2, b2, nbr, out);
}